// Round 12
// baseline (94.195 us; speedup 1.0000x reference)
//
#include <hip/hip_runtime.h>
#include <hip/hip_fp16.h>

#define B_DIM   128
#define N_IN    16384
#define N_OUT   8192
#define N_EDGES (N_OUT * 64)

#define CHUNKB  64                  // batch cols per pass (2 MB fp16 slab)
#define NPASS   (B_DIM / CHUNKB)    // 2

#define J_BLK    8                  // outputs (waves) per block
#define THREADS  (J_BLK * 64)       // 512
#define JGROUPS  (N_OUT / J_BLK)    // 1024

__device__ __forceinline__ int lower_bound_dev(const int* __restrict__ a, int n, int v) {
    int lo = 0, hi = n;
    while (lo < hi) {
        int mid = (lo + hi) >> 1;
        if (a[mid] < v) lo = mid + 1; else hi = mid;
    }
    return lo;
}

// rp[j] = first edge index with dst >= j (j in [0, N_OUT]), via boundary scatter.
__global__ void build_rowptr_kernel(const int* __restrict__ dst, int* __restrict__ rp) {
    const int e = blockIdx.x * blockDim.x + threadIdx.x;
    if (e >= N_EDGES) return;
    const int d     = __builtin_nontemporal_load(dst + e);
    const int dprev = (e == 0) ? -1 : __builtin_nontemporal_load(dst + e - 1);
    for (int j = dprev + 1; j <= d; ++j) rp[j] = e;
    if (e == N_EDGES - 1)
        for (int j = d + 1; j <= N_OUT; ++j) rp[j] = N_EDGES;
}

// x[B][N_IN] (fp32) -> xC[pass][N_IN][CHUNKB] (fp16): per-pass CONTIGUOUS 2 MB
// slab of 128B rows. Read coalesced (nt: x streamed once), slab rows written
// as 32 consecutive half2 per 32-lane row (128B contiguous stores).
__global__ __launch_bounds__(256) void transpose_c_kernel(const float* __restrict__ x,
                                                          __half* __restrict__ xC) {
    __shared__ float tile[64][33];      // [b_local][i_local]
    const int i0   = blockIdx.x * 32;
    const int b0   = blockIdx.y * 64;   // grid.y = 2 -> b0 = 0 or 64 = pass slab
    const int slab = blockIdx.y;        // pass index
    const int tx   = threadIdx.x;       // 0..31
    const int ty   = threadIdx.y;       // 0..7
#pragma unroll
    for (int r = 0; r < 64; r += 8)
        tile[ty + r][tx] = __builtin_nontemporal_load(&x[(size_t)(b0 + ty + r) * N_IN + (i0 + tx)]);
    __syncthreads();
    __half2* out = (__half2*)xC;
#pragma unroll
    for (int rr = 0; rr < 4; ++rr) {
        const int il = rr * 8 + ty;     // i_local 0..31
        const float a = tile[2 * tx][il];
        const float b = tile[2 * tx + 1][il];
        out[((size_t)slab * N_IN + (i0 + il)) * (CHUNKB / 2) + tx] = __floats2half2_rn(a, b);
    }
}

// One PASS over one 2 MB slab (strictly sequential launches keep the slab
// L2-resident per XCD with 2 MB headroom; nt on all streamed-once traffic).
// One WAVE per output j. Lane = (slot = lane>>3 -> edge within oct,
// bl = lane&7 -> 16B of the 128B row). 8 edges per gather instruction, fp32
// accumulate, 3-step shfl_xor reduce over slots, LDS-transposed epilogue.
__global__ __launch_bounds__(THREADS, 8) void sparse_layer_c(
        const __half* __restrict__ xslab, const float* __restrict__ w,
        const float* __restrict__ bias, const int* __restrict__ src,
        const int* __restrict__ rp, float* __restrict__ y, int boff) {
    __shared__ float tile[J_BLK][68];

    const int tid  = threadIdx.x;
    const int wid  = tid >> 6;
    const int lane = tid & 63;
    const int slot = lane >> 3;         // 0..7
    const int bl   = lane & 7;          // 16B chunk -> chunk cols 8*bl .. 8*bl+7
    const int j0   = blockIdx.x * J_BLK;
    const int j    = j0 + wid;

    const int e0 = __builtin_amdgcn_readfirstlane(rp[j]);
    const int e1 = __builtin_amdgcn_readfirstlane(rp[j + 1]);

    float acc[8] = {0.f, 0.f, 0.f, 0.f, 0.f, 0.f, 0.f, 0.f};
    const char* xbase = (const char*)xslab + bl * 16;   // + row*128B

#pragma unroll 2
    for (int e = e0; e < e1; e += 8) {
        const int  ee    = e + slot;
        const bool valid = ee < e1;
        const int  ec    = valid ? ee : e0;             // e0 < e1 inside loop
        const int  s     = __builtin_nontemporal_load(src + ec);
        const float wt   = valid ? __builtin_nontemporal_load(w + ec) : 0.f;
        const float4 raw = *(const float4*)(xbase + (size_t)s * (CHUNKB * 2));
        const __half2* hp = (const __half2*)&raw;
#pragma unroll
        for (int q = 0; q < 4; ++q) {
            const float2 f = __half22float2(hp[q]);
            acc[2 * q]     = fmaf(f.x, wt, acc[2 * q]);
            acc[2 * q + 1] = fmaf(f.y, wt, acc[2 * q + 1]);
        }
    }

    // Reduce over the 8 edge slots (lane bits 3..5).
#pragma unroll
    for (int m = 8; m <= 32; m <<= 1)
#pragma unroll
        for (int q = 0; q < 8; ++q) acc[q] += __shfl_xor(acc[q], m, 64);

    if (slot == 0) {                    // lanes 0..7 hold chunk cols 8*bl..8*bl+7
#pragma unroll
        for (int q = 0; q < 8; ++q) tile[wid][8 * bl + q] = acc[q];
    }
    __syncthreads();

    // Coalesced epilogue: 8 consecutive lanes -> 8 consecutive j (32B segments).
    // 512 threads = 64 chunk rows x 8 outputs exactly. y write-once -> nt store.
    {
        const int bb = tid >> 3;        // 0..63 chunk-local batch row
        const int jj = tid & (J_BLK - 1);
        const float v = tile[jj][bb] + bias[j0 + jj];
        __builtin_nontemporal_store(fmaxf(v, 0.f), &y[(size_t)(boff + bb) * N_OUT + (j0 + jj)]);
    }
}

// Fallback (no usable workspace): per-output wave, fp32 gathers from row-major x.
__global__ __launch_bounds__(THREADS) void sparse_layer_fallback(
        const float* __restrict__ x, const float* __restrict__ w,
        const float* __restrict__ bias, const int* __restrict__ src,
        const int* __restrict__ dst, float* __restrict__ y) {
    __shared__ float tile[J_BLK][130];
    __shared__ int   srp[J_BLK + 1];

    const int tid  = threadIdx.x;
    const int wid  = tid >> 6;
    const int lane = tid & 63;
    const int j0   = blockIdx.x * J_BLK;

    if (tid <= J_BLK) srp[tid] = lower_bound_dev(dst, N_EDGES, j0 + tid);
    __syncthreads();

    const int e0 = srp[wid], e1 = srp[wid + 1];
    const int b0 = lane * 2;
    float acc0 = 0.f, acc1 = 0.f;
    for (int e = e0; e < e1; ++e) {
        const int   s  = src[e];
        const float wt = w[e];
        acc0 = fmaf(x[(size_t)b0 * N_IN + s], wt, acc0);
        acc1 = fmaf(x[(size_t)(b0 + 1) * N_IN + s], wt, acc1);
    }
    tile[wid][b0]     = acc0;
    tile[wid][b0 + 1] = acc1;
    __syncthreads();
#pragma unroll
    for (int i = tid; i < B_DIM * J_BLK; i += THREADS) {
        const int bb = i >> 3;
        const int jj = i & (J_BLK - 1);
        const float v = tile[jj][bb] + bias[j0 + jj];
        y[(size_t)bb * N_OUT + (j0 + jj)] = fmaxf(v, 0.f);
    }
}

extern "C" void kernel_launch(void* const* d_in, const int* in_sizes, int n_in,
                              void* d_out, int out_size, void* d_ws, size_t ws_size,
                              hipStream_t stream) {
    const float* x    = (const float*)d_in[0];
    const float* w    = (const float*)d_in[1];
    const float* bias = (const float*)d_in[2];
    const int*   esrc = (const int*)d_in[3];
    const int*   edst = (const int*)d_in[4];
    float*       y    = (float*)d_out;

    // ws layout: rp [0, 64KB) | xC [64KB, +4MB) (two 2MB pass slabs)
    const size_t XT_OFF   = 65536;
    const size_t XT_BYTES = (size_t)NPASS * N_IN * CHUNKB * sizeof(__half);

    const bool has_ws = ws_size >= XT_OFF + XT_BYTES;

    int*    rp = (int*)d_ws;
    __half* xC = (__half*)((char*)d_ws + XT_OFF);

    if (has_ws) {
        build_rowptr_kernel<<<(N_EDGES + 255) / 256, 256, 0, stream>>>(edst, rp);
        transpose_c_kernel<<<dim3(N_IN / 32, NPASS), dim3(32, 8), 0, stream>>>(x, xC);
        // Two STRICTLY SEQUENTIAL passes (same stream): per-pass gather set is a
        // 2 MB contiguous slab -> L2-resident per XCD with headroom.
        for (int p = 0; p < NPASS; ++p) {
            const __half* xslab = xC + (size_t)p * N_IN * CHUNKB;
            sparse_layer_c<<<dim3(JGROUPS), THREADS, 0, stream>>>(
                xslab, w, bias, esrc, rp, y, p * CHUNKB);
        }
    } else {
        sparse_layer_fallback<<<dim3(N_OUT / J_BLK), THREADS, 0, stream>>>(x, w, bias, esrc, edst, y);
    }
}